// Round 1
// 180.319 us; speedup vs baseline: 1.0785x; 1.0785x over previous
//
#include <hip/hip_runtime.h>
#include <stdint.h>

typedef __bf16 bf16x8 __attribute__((ext_vector_type(8)));
typedef float f32x4 __attribute__((ext_vector_type(4)));

#define B_ 16
#define C_ 512
#define S_ 1024   // W*H = 32*32
#define N1 1536   // 3C

// ---------- bf16 helpers (manual RNE) ----------
__device__ inline unsigned short f2b(float f) {
    unsigned int u = __builtin_bit_cast(unsigned int, f);
    unsigned int lsb = (u >> 16) & 1u;
    u += 0x7fffu + lsb;
    return (unsigned short)(u >> 16);
}
__device__ inline float b2f(unsigned int s) {
    unsigned int u = (s & 0xffffu) << 16;
    return __builtin_bit_cast(float, u);
}

// async global->LDS, 16B per lane. LDS dest must be wave-uniform base + lane*16.
__device__ inline void gl_lds16(const unsigned short* g, unsigned short* l) {
    __builtin_amdgcn_global_load_lds(
        (const __attribute__((address_space(1))) void*)(g),
        (__attribute__((address_space(3))) void*)(l),
        16, 0, 0);
}

// ---------- prep: x (B,C,S) f32 -> xT (B,S,C) bf16, plus fused misc work ----------
// blockIdx.z < 16 : transpose plane for batch z
// blockIdx.z == 16: w1/w2 bf16 convert + zero sum planes (misc_prep fused)
__global__ void transpose_convert_x(const float* __restrict__ x, unsigned short* __restrict__ xT,
                                    const float* __restrict__ w1, const float* __restrict__ w2,
                                    unsigned short* __restrict__ w1b, unsigned short* __restrict__ w2b,
                                    float* __restrict__ sums) {
    if (blockIdx.z == 16) {
        // 512 blocks x 256 threads, float4-granular: w1 = 196608, w2 = 65536, sums = 30720
        int t = (blockIdx.y * 32 + blockIdx.x) * 256 + threadIdx.y * 32 + threadIdx.x;
#pragma unroll
        for (int it = 0; it < 3; it++) {
            int i = t + it * 131072;
            if (i < 196608) {
                float4 v = ((const float4*)w1)[i];
                ((ushort4*)w1b)[i] = make_ushort4(f2b(v.x), f2b(v.y), f2b(v.z), f2b(v.w));
            } else if (i < 262144) {
                int j = i - 196608;
                float4 v = ((const float4*)w2)[j];
                ((ushort4*)w2b)[j] = make_ushort4(f2b(v.x), f2b(v.y), f2b(v.z), f2b(v.w));
            } else if (i < 292864) {
                int j = i - 262144;
                ((float4*)sums)[j] = make_float4(0.f, 0.f, 0.f, 0.f);
            }
        }
        return;
    }
    __shared__ float tile[32][33];
    int b = blockIdx.z;
    int c0 = blockIdx.y * 32;
    int s0 = blockIdx.x * 32;
    int tx = threadIdx.x, ty = threadIdx.y; // (32,8)
    const float* xp = x + ((size_t)b * C_ + c0) * S_ + s0;
#pragma unroll
    for (int i = 0; i < 4; i++)
        tile[ty + i * 8][tx] = xp[(size_t)(ty + i * 8) * S_ + tx];
    __syncthreads();
    unsigned short* op = xT + ((size_t)b * S_ + s0) * C_ + c0;
#pragma unroll
    for (int i = 0; i < 4; i++)
        op[(size_t)(ty + i * 8) * C_ + tx] = f2b(tile[tx][ty + i * 8]);
}

// ---------- GEMM: C[m,n] = A[m,:] . Wt[n,:] + bias[n], K=512 ----------
// BK=64 double-depth K-step (8 barrier pairs instead of 16), 128B LDS rows with
// XOR-swizzle (rule #21): linear LDS dest, inverse-swizzled global SOURCE,
// same XOR on the ds_read side -> 2-way bank aliasing (free).
// DO_SUMS: accumulate T/H0/H31/C0/C31 planes (16x1536 each) for the gating a-sum.
// TRANS_OUT: store f32 out[(b*512+n)*1024 + s], m = b*1024+s (N=512).
template <bool TRANS_OUT, bool DO_SUMS>
__global__ __launch_bounds__(256) void gemm_bf16(
    const unsigned short* __restrict__ A,
    const unsigned short* __restrict__ Wt,
    const float* __restrict__ bias,
    void* __restrict__ Cout, int N,
    float* __restrict__ Tsum, float* __restrict__ H0, float* __restrict__ H31,
    float* __restrict__ C0, float* __restrict__ C31)
{
    const int K = 512;
    __shared__ __align__(16) unsigned short As[128 * 64]; // 16 KB, 128B rows (swizzled)
    __shared__ __align__(16) unsigned short Bs[128 * 64];
    int m0 = blockIdx.x * 128;
    int n0 = blockIdx.y * 128;
    int tid = threadIdx.x;
    int lane = tid & 63, wid = tid >> 6;
    int wm = (wid >> 1) * 64, wn = (wid & 1) * 64;
    int quad = lane >> 4, l16 = lane & 15;
    const unsigned short* Ab = A + (size_t)m0 * K;
    const unsigned short* Bb = Wt + (size_t)n0 * K;

    f32x4 acc[4][4] = {};

    for (int kt = 0; kt < K; kt += 64) {
        __syncthreads();
#pragma unroll
        for (int i = 0; i < 4; i++) {
            int ch = i * 256 + tid;          // 16B channel in [0,1024)
            int m = ch >> 3;                 // row 0..127
            int kc = (ch & 7) ^ (m & 7);     // inverse-swizzled source k-chunk
            size_t go = (size_t)m * K + kt + kc * 8;
            gl_lds16(Ab + go, &As[ch * 8]);
            gl_lds16(Bb + go, &Bs[ch * 8]);
        }
        __syncthreads();
#pragma unroll
        for (int kh = 0; kh < 2; kh++) {
            bf16x8 af[4], bfr[4];
#pragma unroll
            for (int t = 0; t < 4; t++) {
                int ra = wm + t * 16 + l16;
                int rb = wn + t * 16 + l16;
                int kq = kh * 4 + quad;
                af[t]  = *(const bf16x8*)&As[ra * 64 + ((kq ^ (ra & 7)) * 8)];
                bfr[t] = *(const bf16x8*)&Bs[rb * 64 + ((kq ^ (rb & 7)) * 8)];
            }
#pragma unroll
            for (int mt = 0; mt < 4; mt++)
#pragma unroll
                for (int nt = 0; nt < 4; nt++)
                    acc[mt][nt] = __builtin_amdgcn_mfma_f32_16x16x32_bf16(af[mt], bfr[nt], acc[mt][nt], 0, 0, 0);
        }
    }

    // ---- write output ----
#pragma unroll
    for (int mt = 0; mt < 4; mt++) {
#pragma unroll
        for (int nt = 0; nt < 4; nt++) {
            int n = n0 + wn + nt * 16 + l16;
            float bv = bias[n];
            int mbase = m0 + wm + mt * 16 + quad * 4;
            if (!TRANS_OUT) {
                unsigned short* Y = (unsigned short*)Cout;
#pragma unroll
                for (int r = 0; r < 4; r++)
                    Y[(size_t)(mbase + r) * N + n] = f2b(acc[mt][nt][r] + bv);
            } else {
                float* Z = (float*)Cout;
                int b = mbase >> 10;
                int s = mbase & 1023;
                float4 v = make_float4(acc[mt][nt][0] + bv, acc[mt][nt][1] + bv,
                                       acc[mt][nt][2] + bv, acc[mt][nt][3] + bv);
                *(float4*)(&Z[((size_t)(b * 512 + n)) * 1024 + s]) = v;
            }
        }
    }

    // ---- fused a-sum accumulators ----
    // m_local = wm + mt*16 + quad*4 + r; h = m_local&31; w = wlo + (m_local>>5)
    if (DO_SUMS) {
        int b = m0 >> 10;
        int wlo = (m0 & 1023) >> 5; // first of 4 w-rows in this block
#pragma unroll
        for (int nt = 0; nt < 4; nt++) {
            int n = n0 + wn + nt * 16 + l16;
            float bv = bias[n];
            // total over this wave's 64 m's
            float tT = 0.f;
#pragma unroll
            for (int mt = 0; mt < 4; mt++)
#pragma unroll
                for (int r = 0; r < 4; r++) tT += acc[mt][nt][r] + bv;
            tT += __shfl_xor(tT, 16);
            tT += __shfl_xor(tT, 32);
            if (quad == 0) {
                atomicAdd(&Tsum[b * 1536 + n], tT);
                // h==0 rows: m_local = wm+{0,32} -> (mt 0,2, quad0, r0)
                float th0 = acc[0][nt][0] + acc[2][nt][0] + 2.f * bv;
                atomicAdd(&H0[b * 1536 + n], th0);
            }
            if (quad == 3) {
                // h==31 rows: m_local = wm+{31,63} -> (mt 1,3, quad3, r3)
                float th31 = acc[1][nt][3] + acc[3][nt][3] + 2.f * bv;
                atomicAdd(&H31[b * 1536 + n], th31);
            }
            if (wlo == 0 && wm == 0) { // w==0 slice: m_local < 32 -> mt 0,1
                float tc = 0.f;
#pragma unroll
                for (int mt = 0; mt < 2; mt++)
#pragma unroll
                    for (int r = 0; r < 4; r++) tc += acc[mt][nt][r] + bv;
                tc += __shfl_xor(tc, 16);
                tc += __shfl_xor(tc, 32);
                if (quad == 0) atomicAdd(&C0[b * 1536 + n], tc);
            }
            if (wlo == 28 && wm == 64) { // w==31 slice: m_local >= 96 -> mt 2,3
                float tc = 0.f;
#pragma unroll
                for (int mt = 2; mt < 4; mt++)
#pragma unroll
                    for (int r = 0; r < 4; r++) tc += acc[mt][nt][r] + bv;
                tc += __shfl_xor(tc, 16);
                tc += __shfl_xor(tc, 32);
                if (quad == 0) atomicAdd(&C31[b * 1536 + n], tc);
            }
        }
    }
}

// ---------- layer1: reconstruct a[b,:] from sum planes, then wave-dot ----------
// a[b,c]: q=c>>7, sgn=(q&1)?-1:+1,
//   e = (q<2) ? (C0-C31)[n1]+(H0-H31)[n2] : (H0-H31)[n1]+(C0-C31)[n2]
//   a = T[n1]+T[n2]+T[n3] + sgn*e       (n1=c, n2=512+c, n3=1024+c)
__global__ __launch_bounds__(256) void mlp_layer1(
    const float* __restrict__ sums, const float* __restrict__ wa,
    const float* __restrict__ ba, float* __restrict__ h)
{
    __shared__ float sa[512];
    int b = blockIdx.x >> 7;
    int t = threadIdx.x;
    const float* Tp   = sums;
    const float* H0p  = sums + 24576;
    const float* H31p = sums + 49152;
    const float* C0p  = sums + 73728;
    const float* C31p = sums + 98304;
#pragma unroll
    for (int j = 0; j < 2; j++) {
        int c = t + j * 256;
        int q = c >> 7;
        int n1 = b * 1536 + c;
        float t123 = Tp[n1] + Tp[n1 + 512] + Tp[n1 + 1024];
        float sC1 = C0p[n1] - C31p[n1];
        float sH1 = H0p[n1] - H31p[n1];
        float sC2 = C0p[n1 + 512] - C31p[n1 + 512];
        float sH2 = H0p[n1 + 512] - H31p[n1 + 512];
        float e = (q < 2) ? (sC1 + sH2) : (sH1 + sC2);
        sa[c] = t123 + ((q & 1) ? -e : e);
    }
    __syncthreads();
    int lane = t & 63, wid = t >> 6;
    int o = (blockIdx.x & 127) * 4 + wid;
    const float4* wr = (const float4*)(wa + (size_t)o * 512);
    float4 w0 = wr[lane * 2], w1v = wr[lane * 2 + 1];
    float4 a0 = ((const float4*)sa)[lane * 2], a1 = ((const float4*)sa)[lane * 2 + 1];
    float dot = w0.x * a0.x + w0.y * a0.y + w0.z * a0.z + w0.w * a0.w
              + w1v.x * a1.x + w1v.y * a1.y + w1v.z * a1.z + w1v.w * a1.w;
#pragma unroll
    for (int off = 32; off; off >>= 1) dot += __shfl_down(dot, off);
    if (lane == 0) {
        float v = dot + ba[o];
        h[b * 512 + o] = 0.5f * v * (1.0f + erff(v * 0.7071067811865475f));
    }
}

// ---------- layer2: hat[b*1536+o] = dot(h[b,:], wb[o,:]) + bb[o] ----------
__global__ __launch_bounds__(256) void mlp_layer2(
    const float* __restrict__ h, const float* __restrict__ wb,
    const float* __restrict__ bb, float* __restrict__ hat)
{
    int gw = (blockIdx.x * 256 + threadIdx.x) >> 6; // 24576 waves
    int lane = threadIdx.x & 63;
    int b = gw / 1536;
    int o = gw - b * 1536;
    const float4* wr = (const float4*)(wb + (size_t)o * 512);
    const float4* hr = (const float4*)(h + (size_t)b * 512);
    float4 w0 = wr[lane * 2], w1 = wr[lane * 2 + 1];
    float4 h0 = hr[lane * 2], h1 = hr[lane * 2 + 1];
    float dot = w0.x * h0.x + w0.y * h0.y + w0.z * h0.z + w0.w * h0.w
              + w1.x * h1.x + w1.y * h1.y + w1.z * h1.z + w1.w * h1.w;
#pragma unroll
    for (int off = 32; off; off >>= 1) dot += __shfl_down(dot, off);
    if (lane == 0)
        hat[(size_t)b * 1536 + o] = dot + bb[o];
}

// ---------- combine (softmax inline): out[b,s,c] = sum_j g_j * x_j (bf16) ----------
// (b,w) per block -> 512 blocks (full CU coverage); each wave owns 8 h-rows.
__global__ __launch_bounds__(256) void combine_softmax(
    const unsigned short* __restrict__ y, const float* __restrict__ hat,
    unsigned short* __restrict__ outT)
{
    int b = blockIdx.y;
    int w = blockIdx.x;          // 0..31
    int t = threadIdx.x;
    int h0 = (t >> 6) * 8;       // wave -> 8 consecutive h rows
    int c8 = (t & 63) * 8;
    int q = c8 >> 7;
    int dw1 = (q == 0) ? -1 : (q == 1) ? 1 : 0;
    int dh1 = (q == 2) ? -1 : (q == 3) ? 1 : 0;
    int dh2 = (q == 0) ? -1 : (q == 1) ? 1 : 0;
    int dw2 = (q == 2) ? -1 : (q == 3) ? 1 : 0;
    float g0[8], g1[8], g2[8];
#pragma unroll
    for (int j = 0; j < 8; j++) {
        int c = c8 + j;
        float h0v = hat[b * 1536 + c];
        float h1v = hat[b * 1536 + 512 + c];
        float h2v = hat[b * 1536 + 1024 + c];
        float mx = fmaxf(h0v, fmaxf(h1v, h2v));
        float e0 = __expf(h0v - mx), e1 = __expf(h1v - mx), e2 = __expf(h2v - mx);
        float inv = 1.0f / (e0 + e1 + e2);
        g0[j] = e0 * inv; g1[j] = e1 * inv; g2[j] = e2 * inv;
    }
    int w1i = min(max(w + dw1, 0), 31);
    int w2i = min(max(w + dw2, 0), 31);
    size_t base = (size_t)b * S_;
#pragma unroll
    for (int hh = 0; hh < 8; hh++) {
        int h = h0 + hh;
        int h1i = min(max(h + dh1, 0), 31);
        int h2i = min(max(h + dh2, 0), 31);
        uint4 u1 = *(const uint4*)&y[(base + w1i * 32 + h1i) * N1 + c8];
        uint4 u2 = *(const uint4*)&y[(base + w2i * 32 + h2i) * N1 + 512 + c8];
        uint4 u3 = *(const uint4*)&y[(base + w * 32 + h) * N1 + 1024 + c8];
        unsigned int p[4];
        const unsigned int* a1 = &u1.x;
        const unsigned int* a2 = &u2.x;
        const unsigned int* a3 = &u3.x;
#pragma unroll
        for (int k = 0; k < 4; k++) {
            int j = k * 2;
            float lo = g0[j] * b2f(a1[k]) + g1[j] * b2f(a2[k]) + g2[j] * b2f(a3[k]);
            float hi = g0[j + 1] * b2f(a1[k] >> 16) + g1[j + 1] * b2f(a2[k] >> 16) + g2[j + 1] * b2f(a3[k] >> 16);
            p[k] = (unsigned int)f2b(lo) | ((unsigned int)f2b(hi) << 16);
        }
        *(uint4*)&outT[(base + w * 32 + h) * 512 + c8] = make_uint4(p[0], p[1], p[2], p[3]);
    }
}

extern "C" void kernel_launch(void* const* d_in, const int* in_sizes, int n_in,
                              void* d_out, int out_size, void* d_ws, size_t ws_size,
                              hipStream_t stream) {
    const float* x  = (const float*)d_in[0];
    const float* w1 = (const float*)d_in[1];
    const float* b1 = (const float*)d_in[2];
    const float* wa = (const float*)d_in[3];
    const float* ba = (const float*)d_in[4];
    const float* wb = (const float*)d_in[5];
    const float* bb = (const float*)d_in[6];
    const float* w2 = (const float*)d_in[7];
    const float* b2 = (const float*)d_in[8];
    float* out = (float*)d_out;

    char* ws = (char*)d_ws;
    unsigned short* xT   = (unsigned short*)(ws);              // 16 MB (dead after gemm1)
    unsigned short* outT = (unsigned short*)(ws);              // aliases xT (combine runs after gemm1)
    unsigned short* w1b  = (unsigned short*)(ws + 16777216);   // 1.5 MB
    unsigned short* w2b  = (unsigned short*)(ws + 18350080);   // 0.5 MB
    unsigned short* y    = (unsigned short*)(ws + 18874368);   // 48 MB: (B,S,3C) bf16
    float* sums          = (float*)(ws + 69206016);            // 5 x 96 KB: T,H0,H31,C0,C31
    float* h_buf         = (float*)(ws + 69697536);            // 32 KB
    float* hat_buf       = (float*)(ws + 69730304);            // 96 KB

    float* Tsum = sums;
    float* H0   = sums + 24576;
    float* H31  = sums + 49152;
    float* C0   = sums + 73728;
    float* C31  = sums + 98304;

    // z==16 plane does the fused misc_prep (w1/w2 convert + sum-plane zero)
    transpose_convert_x<<<dim3(32, 16, 17), dim3(32, 8), 0, stream>>>(
        x, xT, w1, w2, w1b, w2b, sums);
    gemm_bf16<false, true><<<dim3(128, 12), dim3(256), 0, stream>>>(
        xT, w1b, b1, (void*)y, 1536, Tsum, H0, H31, C0, C31);
    mlp_layer1<<<dim3(2048), dim3(256), 0, stream>>>(sums, wa, ba, h_buf);
    mlp_layer2<<<dim3(6144), dim3(256), 0, stream>>>(h_buf, wb, bb, hat_buf);
    combine_softmax<<<dim3(32, 16), dim3(256), 0, stream>>>(y, hat_buf, outT);
    gemm_bf16<true, false><<<dim3(128, 4), dim3(256), 0, stream>>>(
        outT, w2b, b2, (void*)out, 512, nullptr, nullptr, nullptr, nullptr, nullptr);
}

// Round 2
// 178.038 us; speedup vs baseline: 1.0923x; 1.0128x over previous
//
#include <hip/hip_runtime.h>
#include <stdint.h>

typedef __bf16 bf16x8 __attribute__((ext_vector_type(8)));
typedef float f32x4 __attribute__((ext_vector_type(4)));

#define B_ 16
#define C_ 512
#define S_ 1024   // W*H = 32*32
#define N1 1536   // 3C

// ---------- bf16 helpers (manual RNE) ----------
__device__ inline unsigned short f2b(float f) {
    unsigned int u = __builtin_bit_cast(unsigned int, f);
    unsigned int lsb = (u >> 16) & 1u;
    u += 0x7fffu + lsb;
    return (unsigned short)(u >> 16);
}
__device__ inline float b2f(unsigned int s) {
    unsigned int u = (s & 0xffffu) << 16;
    return __builtin_bit_cast(float, u);
}

// async global->LDS, 16B per lane. LDS dest must be wave-uniform base + lane*16.
__device__ inline void gl_lds16(const unsigned short* g, unsigned short* l) {
    __builtin_amdgcn_global_load_lds(
        (const __attribute__((address_space(1))) void*)(g),
        (__attribute__((address_space(3))) void*)(l),
        16, 0, 0);
}

// ---------- prep: x (B,C,S) f32 -> xT (B,S,C) bf16, plus fused misc work ----------
__global__ void transpose_convert_x(const float* __restrict__ x, unsigned short* __restrict__ xT,
                                    const float* __restrict__ w1, const float* __restrict__ w2,
                                    unsigned short* __restrict__ w1b, unsigned short* __restrict__ w2b,
                                    float* __restrict__ sums) {
    if (blockIdx.z == 16) {
        int t = (blockIdx.y * 32 + blockIdx.x) * 256 + threadIdx.y * 32 + threadIdx.x;
#pragma unroll
        for (int it = 0; it < 3; it++) {
            int i = t + it * 131072;
            if (i < 196608) {
                float4 v = ((const float4*)w1)[i];
                ((ushort4*)w1b)[i] = make_ushort4(f2b(v.x), f2b(v.y), f2b(v.z), f2b(v.w));
            } else if (i < 262144) {
                int j = i - 196608;
                float4 v = ((const float4*)w2)[j];
                ((ushort4*)w2b)[j] = make_ushort4(f2b(v.x), f2b(v.y), f2b(v.z), f2b(v.w));
            } else if (i < 292864) {
                int j = i - 262144;
                ((float4*)sums)[j] = make_float4(0.f, 0.f, 0.f, 0.f);
            }
        }
        return;
    }
    __shared__ float tile[32][33];
    int b = blockIdx.z;
    int c0 = blockIdx.y * 32;
    int s0 = blockIdx.x * 32;
    int tx = threadIdx.x, ty = threadIdx.y; // (32,8)
    const float* xp = x + ((size_t)b * C_ + c0) * S_ + s0;
#pragma unroll
    for (int i = 0; i < 4; i++)
        tile[ty + i * 8][tx] = xp[(size_t)(ty + i * 8) * S_ + tx];
    __syncthreads();
    unsigned short* op = xT + ((size_t)b * S_ + s0) * C_ + c0;
#pragma unroll
    for (int i = 0; i < 4; i++)
        op[(size_t)(ty + i * 8) * C_ + tx] = f2b(tile[tx][ty + i * 8]);
}

// ---------- gemm1: 256x256 tile, BK=64, 8 waves, 8-phase counted-vmcnt schedule ----------
// A[16384][512] bf16, Wt[1536][512] bf16 -> Y[16384][1536] bf16 (+bias), + sum planes.
// LDS ring: 8 slots x 16KB. slot(T,part) = (T&1)*4 + part; part 0=A_lo 1=A_hi 2=B_lo 3=B_hi.
// Stage stream: prologue {B0lo,B0hi,A0lo,A0hi,B1lo,B1hi}; tile T phases stage
// {A(T+1)lo, A(T+1)hi, B(T+2)lo, B(T+2)hi}. vmcnt(4) at each tile end keeps the
// 2 newest half-tiles (next-next B) in flight -- never drains until T==6.
// Swizzle (proven R1, 0 conflicts): source k-chunk kc^(r&7), read chunk kq^(row&7).
__global__ __launch_bounds__(512, 2) void gemm1_8ph(
    const unsigned short* __restrict__ A,
    const unsigned short* __restrict__ Wt,
    const float* __restrict__ bias,
    unsigned short* __restrict__ Y,
    float* __restrict__ Tsum, float* __restrict__ H0, float* __restrict__ H31,
    float* __restrict__ C0, float* __restrict__ C31)
{
    __shared__ __align__(16) unsigned short lds[8 * 8192]; // 128 KB
    const int tid = threadIdx.x;
    const int lane = tid & 63, wid = tid >> 6;
    const int wm = (wid >> 2) * 128;   // 0 or 128 (A half)
    const int wn = (wid & 3) * 64;     // 0,64,128,192
    const int quad = lane >> 4, l16 = lane & 15;
    const int m0 = blockIdx.x * 256;
    const int n0 = blockIdx.y * 256;
    const int ahalf = wid >> 2;        // which A half this wave reads
    const int bhalf = (wid & 3) >> 1;  // which B half
    const int rb0 = (wid & 1) * 64;    // row base within B half
    const unsigned short* Ab = A + (size_t)m0 * 512;
    const unsigned short* Bb = Wt + (size_t)n0 * 512;

    f32x4 acc[8][4] = {};

    auto stage = [&](int T, int part) {
        const unsigned short* src = (part < 2) ? (Ab + (size_t)part * 128 * 512)
                                               : (Bb + (size_t)(part - 2) * 128 * 512);
        unsigned short* dst = &lds[(size_t)((T & 1) * 4 + part) * 8192];
#pragma unroll
        for (int i = 0; i < 2; i++) {
            int ch = i * 512 + tid;
            int r = ch >> 3, kc = ch & 7;
            size_t go = (size_t)r * 512 + T * 64 + ((kc ^ (r & 7)) * 8);
            gl_lds16(src + go, dst + ch * 8);
        }
    };

    // prologue: tile0 complete (B first), tile1 B halves
    stage(0, 2); stage(0, 3); stage(0, 0); stage(0, 1);
    stage(1, 2); stage(1, 3);
    asm volatile("s_waitcnt vmcnt(4)" ::: "memory"); // tile 0 landed; B1 in flight
    __builtin_amdgcn_s_barrier();

    bf16x8 bfr[4][2];
    for (int T = 0; T < 8; T++) {
        const unsigned short* Asl = &lds[(size_t)((T & 1) * 4 + ahalf) * 8192];
        const unsigned short* Bsl = &lds[(size_t)((T & 1) * 4 + 2 + bhalf) * 8192];
#pragma unroll
        for (int sg = 0; sg < 4; sg++) {
            bf16x8 af[2][2];
            if (sg == 0) {
#pragma unroll
                for (int n = 0; n < 4; n++)
#pragma unroll
                    for (int kh = 0; kh < 2; kh++) {
                        int rb = rb0 + n * 16 + l16;
                        bfr[n][kh] = *(const bf16x8*)&Bsl[rb * 64 + (((kh * 4 + quad) ^ (rb & 7)) * 8)];
                    }
            }
#pragma unroll
            for (int mi = 0; mi < 2; mi++)
#pragma unroll
                for (int kh = 0; kh < 2; kh++) {
                    int ra = (sg * 2 + mi) * 16 + l16;
                    af[mi][kh] = *(const bf16x8*)&Asl[ra * 64 + (((kh * 4 + quad) ^ (ra & 7)) * 8)];
                }
            // staging stream (uniform branches)
            if (sg == 0) { if (T < 7) stage(T + 1, 0); }
            else if (sg == 1) { if (T < 7) stage(T + 1, 1); }
            else if (sg == 2) { if (T < 6) stage(T + 2, 2); }
            else { // sg == 3: tile-boundary counted wait
                if (T < 6) stage(T + 2, 3);
                if (T < 6)       asm volatile("s_waitcnt vmcnt(4)" ::: "memory");
                else if (T == 6) asm volatile("s_waitcnt vmcnt(0)" ::: "memory");
            }
            __builtin_amdgcn_s_barrier();
            asm volatile("s_waitcnt lgkmcnt(0)" ::: "memory");
            __builtin_amdgcn_sched_barrier(0);
            __builtin_amdgcn_s_setprio(1);
#pragma unroll
            for (int mi = 0; mi < 2; mi++)
#pragma unroll
                for (int n = 0; n < 4; n++)
#pragma unroll
                    for (int kh = 0; kh < 2; kh++)
                        acc[sg * 2 + mi][n] = __builtin_amdgcn_mfma_f32_16x16x32_bf16(
                            af[mi][kh], bfr[n][kh], acc[sg * 2 + mi][n], 0, 0, 0);
            __builtin_amdgcn_s_setprio(0);
            __builtin_amdgcn_s_barrier();
        }
    }

    // ---- write y ----
#pragma unroll
    for (int m = 0; m < 8; m++)
#pragma unroll
        for (int nt = 0; nt < 4; nt++) {
            int n = n0 + wn + nt * 16 + l16;
            float bv = bias[n];
            int mbase = m0 + wm + m * 16 + quad * 4;
#pragma unroll
            for (int r = 0; r < 4; r++)
                Y[(size_t)(mbase + r) * N1 + n] = f2b(acc[m][nt][r] + bv);
        }

    // ---- fused a-sum accumulators ----
    // row-in-block = wm + m*16 + quad*4 + r; h = row&31; w = wlo + (row>>5)
    {
        int b = m0 >> 10;
        int wlo = (m0 & 1023) >> 5; // 0,8,16,24
#pragma unroll
        for (int nt = 0; nt < 4; nt++) {
            int n = n0 + wn + nt * 16 + l16;
            float bv = bias[n];
            float tT = 0.f;
#pragma unroll
            for (int m = 0; m < 8; m++)
#pragma unroll
                for (int r = 0; r < 4; r++) tT += acc[m][nt][r] + bv;
            tT += __shfl_xor(tT, 16);
            tT += __shfl_xor(tT, 32);
            if (quad == 0) {
                atomicAdd(&Tsum[b * 1536 + n], tT);
                // h==0: m even, quad==0, r==0 (4 rows per wave)
                float th0 = acc[0][nt][0] + acc[2][nt][0] + acc[4][nt][0] + acc[6][nt][0] + 4.f * bv;
                atomicAdd(&H0[b * 1536 + n], th0);
            }
            if (quad == 3) {
                // h==31: m odd, quad==3, r==3
                float th31 = acc[1][nt][3] + acc[3][nt][3] + acc[5][nt][3] + acc[7][nt][3] + 4.f * bv;
                atomicAdd(&H31[b * 1536 + n], th31);
            }
            if (wlo == 0 && wm == 0) { // w==0: rows 0..31 -> m 0,1
                float tc = 0.f;
#pragma unroll
                for (int m = 0; m < 2; m++)
#pragma unroll
                    for (int r = 0; r < 4; r++) tc += acc[m][nt][r] + bv;
                tc += __shfl_xor(tc, 16);
                tc += __shfl_xor(tc, 32);
                if (quad == 0) atomicAdd(&C0[b * 1536 + n], tc);
            }
            if (wlo == 24 && wm == 128) { // w==31: rows 224..255 -> m 6,7
                float tc = 0.f;
#pragma unroll
                for (int m = 6; m < 8; m++)
#pragma unroll
                    for (int r = 0; r < 4; r++) tc += acc[m][nt][r] + bv;
                tc += __shfl_xor(tc, 16);
                tc += __shfl_xor(tc, 32);
                if (quad == 0) atomicAdd(&C31[b * 1536 + n], tc);
            }
        }
    }
}

// ---------- gemm2 (unchanged R1 structure): 128x128, BK=64, swizzled ----------
template <bool TRANS_OUT>
__global__ __launch_bounds__(256) void gemm_bf16(
    const unsigned short* __restrict__ A,
    const unsigned short* __restrict__ Wt,
    const float* __restrict__ bias,
    void* __restrict__ Cout, int N)
{
    const int K = 512;
    __shared__ __align__(16) unsigned short As[128 * 64];
    __shared__ __align__(16) unsigned short Bs[128 * 64];
    int m0 = blockIdx.x * 128;
    int n0 = blockIdx.y * 128;
    int tid = threadIdx.x;
    int lane = tid & 63, wid = tid >> 6;
    int wm = (wid >> 1) * 64, wn = (wid & 1) * 64;
    int quad = lane >> 4, l16 = lane & 15;
    const unsigned short* Ab = A + (size_t)m0 * K;
    const unsigned short* Bb = Wt + (size_t)n0 * K;

    f32x4 acc[4][4] = {};

    for (int kt = 0; kt < K; kt += 64) {
        __syncthreads();
#pragma unroll
        for (int i = 0; i < 4; i++) {
            int ch = i * 256 + tid;
            int m = ch >> 3;
            int kc = (ch & 7) ^ (m & 7);
            size_t go = (size_t)m * K + kt + kc * 8;
            gl_lds16(Ab + go, &As[ch * 8]);
            gl_lds16(Bb + go, &Bs[ch * 8]);
        }
        __syncthreads();
#pragma unroll
        for (int kh = 0; kh < 2; kh++) {
            bf16x8 af[4], bfr[4];
#pragma unroll
            for (int t = 0; t < 4; t++) {
                int ra = wm + t * 16 + l16;
                int rb = wn + t * 16 + l16;
                int kq = kh * 4 + quad;
                af[t]  = *(const bf16x8*)&As[ra * 64 + ((kq ^ (ra & 7)) * 8)];
                bfr[t] = *(const bf16x8*)&Bs[rb * 64 + ((kq ^ (rb & 7)) * 8)];
            }
#pragma unroll
            for (int mt = 0; mt < 4; mt++)
#pragma unroll
                for (int nt = 0; nt < 4; nt++)
                    acc[mt][nt] = __builtin_amdgcn_mfma_f32_16x16x32_bf16(af[mt], bfr[nt], acc[mt][nt], 0, 0, 0);
        }
    }

#pragma unroll
    for (int mt = 0; mt < 4; mt++) {
#pragma unroll
        for (int nt = 0; nt < 4; nt++) {
            int n = n0 + wn + nt * 16 + l16;
            float bv = bias[n];
            int mbase = m0 + wm + mt * 16 + quad * 4;
            if (!TRANS_OUT) {
                unsigned short* Yp = (unsigned short*)Cout;
#pragma unroll
                for (int r = 0; r < 4; r++)
                    Yp[(size_t)(mbase + r) * N + n] = f2b(acc[mt][nt][r] + bv);
            } else {
                float* Z = (float*)Cout;
                int b = mbase >> 10;
                int s = mbase & 1023;
                float4 v = make_float4(acc[mt][nt][0] + bv, acc[mt][nt][1] + bv,
                                       acc[mt][nt][2] + bv, acc[mt][nt][3] + bv);
                *(float4*)(&Z[((size_t)(b * 512 + n)) * 1024 + s]) = v;
            }
        }
    }
}

// ---------- layer1 ----------
__global__ __launch_bounds__(256) void mlp_layer1(
    const float* __restrict__ sums, const float* __restrict__ wa,
    const float* __restrict__ ba, float* __restrict__ h)
{
    __shared__ float sa[512];
    int b = blockIdx.x >> 7;
    int t = threadIdx.x;
    const float* Tp   = sums;
    const float* H0p  = sums + 24576;
    const float* H31p = sums + 49152;
    const float* C0p  = sums + 73728;
    const float* C31p = sums + 98304;
#pragma unroll
    for (int j = 0; j < 2; j++) {
        int c = t + j * 256;
        int q = c >> 7;
        int n1 = b * 1536 + c;
        float t123 = Tp[n1] + Tp[n1 + 512] + Tp[n1 + 1024];
        float sC1 = C0p[n1] - C31p[n1];
        float sH1 = H0p[n1] - H31p[n1];
        float sC2 = C0p[n1 + 512] - C31p[n1 + 512];
        float sH2 = H0p[n1 + 512] - H31p[n1 + 512];
        float e = (q < 2) ? (sC1 + sH2) : (sH1 + sC2);
        sa[c] = t123 + ((q & 1) ? -e : e);
    }
    __syncthreads();
    int lane = t & 63, wid = t >> 6;
    int o = (blockIdx.x & 127) * 4 + wid;
    const float4* wr = (const float4*)(wa + (size_t)o * 512);
    float4 w0 = wr[lane * 2], w1v = wr[lane * 2 + 1];
    float4 a0 = ((const float4*)sa)[lane * 2], a1 = ((const float4*)sa)[lane * 2 + 1];
    float dot = w0.x * a0.x + w0.y * a0.y + w0.z * a0.z + w0.w * a0.w
              + w1v.x * a1.x + w1v.y * a1.y + w1v.z * a1.z + w1v.w * a1.w;
#pragma unroll
    for (int off = 32; off; off >>= 1) dot += __shfl_down(dot, off);
    if (lane == 0) {
        float v = dot + ba[o];
        h[b * 512 + o] = 0.5f * v * (1.0f + erff(v * 0.7071067811865475f));
    }
}

// ---------- layer2 ----------
__global__ __launch_bounds__(256) void mlp_layer2(
    const float* __restrict__ h, const float* __restrict__ wb,
    const float* __restrict__ bb, float* __restrict__ hat)
{
    int gw = (blockIdx.x * 256 + threadIdx.x) >> 6;
    int lane = threadIdx.x & 63;
    int b = gw / 1536;
    int o = gw - b * 1536;
    const float4* wr = (const float4*)(wb + (size_t)o * 512);
    const float4* hr = (const float4*)(h + (size_t)b * 512);
    float4 w0 = wr[lane * 2], w1 = wr[lane * 2 + 1];
    float4 h0 = hr[lane * 2], h1 = hr[lane * 2 + 1];
    float dot = w0.x * h0.x + w0.y * h0.y + w0.z * h0.z + w0.w * h0.w
              + w1.x * h1.x + w1.y * h1.y + w1.z * h1.z + w1.w * h1.w;
#pragma unroll
    for (int off = 32; off; off >>= 1) dot += __shfl_down(dot, off);
    if (lane == 0)
        hat[(size_t)b * 1536 + o] = dot + bb[o];
}

// ---------- combine (softmax inline) ----------
__global__ __launch_bounds__(256) void combine_softmax(
    const unsigned short* __restrict__ y, const float* __restrict__ hat,
    unsigned short* __restrict__ outT)
{
    int b = blockIdx.y;
    int w = blockIdx.x;          // 0..31
    int t = threadIdx.x;
    int h0 = (t >> 6) * 8;
    int c8 = (t & 63) * 8;
    int q = c8 >> 7;
    int dw1 = (q == 0) ? -1 : (q == 1) ? 1 : 0;
    int dh1 = (q == 2) ? -1 : (q == 3) ? 1 : 0;
    int dh2 = (q == 0) ? -1 : (q == 1) ? 1 : 0;
    int dw2 = (q == 2) ? -1 : (q == 3) ? 1 : 0;
    float g0[8], g1[8], g2[8];
#pragma unroll
    for (int j = 0; j < 8; j++) {
        int c = c8 + j;
        float h0v = hat[b * 1536 + c];
        float h1v = hat[b * 1536 + 512 + c];
        float h2v = hat[b * 1536 + 1024 + c];
        float mx = fmaxf(h0v, fmaxf(h1v, h2v));
        float e0 = __expf(h0v - mx), e1 = __expf(h1v - mx), e2 = __expf(h2v - mx);
        float inv = 1.0f / (e0 + e1 + e2);
        g0[j] = e0 * inv; g1[j] = e1 * inv; g2[j] = e2 * inv;
    }
    int w1i = min(max(w + dw1, 0), 31);
    int w2i = min(max(w + dw2, 0), 31);
    size_t base = (size_t)b * S_;
#pragma unroll
    for (int hh = 0; hh < 8; hh++) {
        int h = h0 + hh;
        int h1i = min(max(h + dh1, 0), 31);
        int h2i = min(max(h + dh2, 0), 31);
        uint4 u1 = *(const uint4*)&y[(base + w1i * 32 + h1i) * N1 + c8];
        uint4 u2 = *(const uint4*)&y[(base + w2i * 32 + h2i) * N1 + 512 + c8];
        uint4 u3 = *(const uint4*)&y[(base + w * 32 + h) * N1 + 1024 + c8];
        unsigned int p[4];
        const unsigned int* a1 = &u1.x;
        const unsigned int* a2 = &u2.x;
        const unsigned int* a3 = &u3.x;
#pragma unroll
        for (int k = 0; k < 4; k++) {
            int j = k * 2;
            float lo = g0[j] * b2f(a1[k]) + g1[j] * b2f(a2[k]) + g2[j] * b2f(a3[k]);
            float hi = g0[j + 1] * b2f(a1[k] >> 16) + g1[j + 1] * b2f(a2[k] >> 16) + g2[j + 1] * b2f(a3[k] >> 16);
            p[k] = (unsigned int)f2b(lo) | ((unsigned int)f2b(hi) << 16);
        }
        *(uint4*)&outT[(base + w * 32 + h) * 512 + c8] = make_uint4(p[0], p[1], p[2], p[3]);
    }
}

extern "C" void kernel_launch(void* const* d_in, const int* in_sizes, int n_in,
                              void* d_out, int out_size, void* d_ws, size_t ws_size,
                              hipStream_t stream) {
    const float* x  = (const float*)d_in[0];
    const float* w1 = (const float*)d_in[1];
    const float* b1 = (const float*)d_in[2];
    const float* wa = (const float*)d_in[3];
    const float* ba = (const float*)d_in[4];
    const float* wb = (const float*)d_in[5];
    const float* bb = (const float*)d_in[6];
    const float* w2 = (const float*)d_in[7];
    const float* b2 = (const float*)d_in[8];
    float* out = (float*)d_out;

    char* ws = (char*)d_ws;
    unsigned short* xT   = (unsigned short*)(ws);              // 16 MB (dead after gemm1)
    unsigned short* outT = (unsigned short*)(ws);              // aliases xT
    unsigned short* w1b  = (unsigned short*)(ws + 16777216);   // 1.5 MB
    unsigned short* w2b  = (unsigned short*)(ws + 18350080);   // 0.5 MB
    unsigned short* y    = (unsigned short*)(ws + 18874368);   // 48 MB: (B,S,3C) bf16
    float* sums          = (float*)(ws + 69206016);            // 5 x 96 KB
    float* h_buf         = (float*)(ws + 69697536);            // 32 KB
    float* hat_buf       = (float*)(ws + 69730304);            // 96 KB

    float* Tsum = sums;
    float* H0   = sums + 24576;
    float* H31  = sums + 49152;
    float* C0   = sums + 73728;
    float* C31  = sums + 98304;

    transpose_convert_x<<<dim3(32, 16, 17), dim3(32, 8), 0, stream>>>(
        x, xT, w1, w2, w1b, w2b, sums);
    gemm1_8ph<<<dim3(64, 6), dim3(512), 0, stream>>>(
        xT, w1b, b1, y, Tsum, H0, H31, C0, C31);
    mlp_layer1<<<dim3(2048), dim3(256), 0, stream>>>(sums, wa, ba, h_buf);
    mlp_layer2<<<dim3(6144), dim3(256), 0, stream>>>(h_buf, wb, bb, hat_buf);
    combine_softmax<<<dim3(32, 16), dim3(256), 0, stream>>>(y, hat_buf, outT);
    gemm_bf16<true><<<dim3(128, 4), dim3(256), 0, stream>>>(
        outT, w2b, b2, (void*)out, 512);
}

// Round 3
// 177.312 us; speedup vs baseline: 1.0968x; 1.0041x over previous
//
#include <hip/hip_runtime.h>
#include <stdint.h>

typedef __bf16 bf16x8 __attribute__((ext_vector_type(8)));
typedef float f32x4 __attribute__((ext_vector_type(4)));

#define B_ 16
#define C_ 512
#define S_ 1024   // W*H = 32*32
#define N1 1536   // 3C

// ---------- bf16 helpers (manual RNE) ----------
__device__ inline unsigned short f2b(float f) {
    unsigned int u = __builtin_bit_cast(unsigned int, f);
    unsigned int lsb = (u >> 16) & 1u;
    u += 0x7fffu + lsb;
    return (unsigned short)(u >> 16);
}
__device__ inline float b2f(unsigned int s) {
    unsigned int u = (s & 0xffffu) << 16;
    return __builtin_bit_cast(float, u);
}

// async global->LDS, 16B per lane. LDS dest must be wave-uniform base + lane*16.
__device__ inline void gl_lds16(const unsigned short* g, unsigned short* l) {
    __builtin_amdgcn_global_load_lds(
        (const __attribute__((address_space(1))) void*)(g),
        (__attribute__((address_space(3))) void*)(l),
        16, 0, 0);
}

// ---------- prep: x (B,C,S) f32 -> xT (B,S,C) bf16, plus fused misc work ----------
__global__ void transpose_convert_x(const float* __restrict__ x, unsigned short* __restrict__ xT,
                                    const float* __restrict__ w1, const float* __restrict__ w2,
                                    unsigned short* __restrict__ w1b, unsigned short* __restrict__ w2b,
                                    float* __restrict__ sums) {
    if (blockIdx.z == 16) {
        int t = (blockIdx.y * 32 + blockIdx.x) * 256 + threadIdx.y * 32 + threadIdx.x;
#pragma unroll
        for (int it = 0; it < 3; it++) {
            int i = t + it * 131072;
            if (i < 196608) {
                float4 v = ((const float4*)w1)[i];
                ((ushort4*)w1b)[i] = make_ushort4(f2b(v.x), f2b(v.y), f2b(v.z), f2b(v.w));
            } else if (i < 262144) {
                int j = i - 196608;
                float4 v = ((const float4*)w2)[j];
                ((ushort4*)w2b)[j] = make_ushort4(f2b(v.x), f2b(v.y), f2b(v.z), f2b(v.w));
            } else if (i < 292864) {
                int j = i - 262144;
                ((float4*)sums)[j] = make_float4(0.f, 0.f, 0.f, 0.f);
            }
        }
        return;
    }
    __shared__ float tile[32][33];
    int b = blockIdx.z;
    int c0 = blockIdx.y * 32;
    int s0 = blockIdx.x * 32;
    int tx = threadIdx.x, ty = threadIdx.y; // (32,8)
    const float* xp = x + ((size_t)b * C_ + c0) * S_ + s0;
#pragma unroll
    for (int i = 0; i < 4; i++)
        tile[ty + i * 8][tx] = xp[(size_t)(ty + i * 8) * S_ + tx];
    __syncthreads();
    unsigned short* op = xT + ((size_t)b * S_ + s0) * C_ + c0;
#pragma unroll
    for (int i = 0; i < 4; i++)
        op[(size_t)(ty + i * 8) * C_ + tx] = f2b(tile[tx][ty + i * 8]);
}

// ---------- gemm: 128x256 tile, BK=64, 8 waves, 2-phase counted-vmcnt schedule ----------
// K=512 fixed. Grid: gemm1 (128,6)=768 blocks (3 exact rounds), gemm2 (128,2)=256 (1 round).
// LDS ring 96 KB: A slots 2x16KB (double buffer, +1 prefetch), B slots 2x32KB (+2 prefetch;
// safe: all B frags register-cached in phase 0, so B slot (T) is dead when B(T+2) lands).
// Phase 0: read B-frags(8) + A-frags m0,m1(4); stage A(T+1); barrier; lgk0; 16 MFMA; barrier.
// Phase 1: read A-frags m2,m3(4); stage B(T+2); vmcnt(4|0); barrier; lgk0; 16 MFMA; barrier.
// Swizzle (HW-proven, 0 conflicts): source k-chunk kc^(r&7), read chunk kq^(row&7).
// Epilogues: vectorized via LDS (reuse ring).
template <bool TRANS_OUT, bool DO_SUMS>
__global__ __launch_bounds__(512, 2) void gemm_2ph(
    const unsigned short* __restrict__ A,
    const unsigned short* __restrict__ Wt,
    const float* __restrict__ bias,
    void* __restrict__ Cout,
    float* __restrict__ Tsum, float* __restrict__ H0, float* __restrict__ H31,
    float* __restrict__ C0, float* __restrict__ C31)
{
    __shared__ __align__(16) unsigned short lds[49152]; // 96 KB
    const int tid = threadIdx.x;
    const int lane = tid & 63, wid = tid >> 6;
    const int wm = (wid >> 2) * 64;   // 0 / 64
    const int wn = (wid & 3) * 64;    // 0,64,128,192
    const int quad = lane >> 4, l16 = lane & 15;
    const int m0 = blockIdx.x * 128;
    const int n0 = blockIdx.y * 256;
    const unsigned short* Ab = A + (size_t)m0 * 512;
    const unsigned short* Bb = Wt + (size_t)n0 * 512;

    f32x4 acc[4][4] = {};

    auto stageA = [&](int T) {
        unsigned short* dst = &lds[(T & 1) * 8192];
#pragma unroll
        for (int i = 0; i < 2; i++) {
            int ch = i * 512 + tid;          // 0..1023, 16B channels
            int r = ch >> 3, kc = ch & 7;
            gl_lds16(Ab + (size_t)r * 512 + T * 64 + ((kc ^ (r & 7)) * 8), dst + ch * 8);
        }
    };
    auto stageB = [&](int T) {
        unsigned short* dst = &lds[16384 + (T & 1) * 16384];
#pragma unroll
        for (int i = 0; i < 4; i++) {
            int ch = i * 512 + tid;          // 0..2047
            int r = ch >> 3, kc = ch & 7;
            gl_lds16(Bb + (size_t)r * 512 + T * 64 + ((kc ^ (r & 7)) * 8), dst + ch * 8);
        }
    };

    // prologue: B0(4), A0(2), B1(4) -> wait oldest 6 (B0,A0), keep B1 in flight
    stageB(0); stageA(0); stageB(1);
    asm volatile("s_waitcnt vmcnt(4)" ::: "memory");
    __builtin_amdgcn_s_barrier();

    for (int T = 0; T < 8; T++) {
        const unsigned short* Asl = &lds[(T & 1) * 8192];
        const unsigned short* Bsl = &lds[16384 + (T & 1) * 16384];
        bf16x8 bfr[4][2], af[2][2];
        // ---- phase 0 ----
#pragma unroll
        for (int nt = 0; nt < 4; nt++)
#pragma unroll
            for (int kh = 0; kh < 2; kh++) {
                int rb = wn + nt * 16 + l16;
                bfr[nt][kh] = *(const bf16x8*)&Bsl[rb * 64 + (((kh * 4 + quad) ^ (rb & 7)) * 8)];
            }
#pragma unroll
        for (int mi = 0; mi < 2; mi++)
#pragma unroll
            for (int kh = 0; kh < 2; kh++) {
                int ra = wm + mi * 16 + l16;
                af[mi][kh] = *(const bf16x8*)&Asl[ra * 64 + (((kh * 4 + quad) ^ (ra & 7)) * 8)];
            }
        if (T < 7) stageA(T + 1);
        __builtin_amdgcn_s_barrier();
        asm volatile("s_waitcnt lgkmcnt(0)" ::: "memory");
        __builtin_amdgcn_sched_barrier(0);
        __builtin_amdgcn_s_setprio(1);
#pragma unroll
        for (int mi = 0; mi < 2; mi++)
#pragma unroll
            for (int nt = 0; nt < 4; nt++)
#pragma unroll
                for (int kh = 0; kh < 2; kh++)
                    acc[mi][nt] = __builtin_amdgcn_mfma_f32_16x16x32_bf16(
                        af[mi][kh], bfr[nt][kh], acc[mi][nt], 0, 0, 0);
        __builtin_amdgcn_s_setprio(0);
        __builtin_amdgcn_s_barrier();
        // ---- phase 1 ----
#pragma unroll
        for (int mi = 0; mi < 2; mi++)
#pragma unroll
            for (int kh = 0; kh < 2; kh++) {
                int ra = wm + (2 + mi) * 16 + l16;
                af[mi][kh] = *(const bf16x8*)&Asl[ra * 64 + (((kh * 4 + quad) ^ (ra & 7)) * 8)];
            }
        if (T < 6) {
            stageB(T + 2);
            asm volatile("s_waitcnt vmcnt(4)" ::: "memory"); // A(T+1),B(T+1) landed; B(T+2) in flight
        } else if (T == 6) {
            asm volatile("s_waitcnt vmcnt(0)" ::: "memory"); // drain A7,B7
        }
        __builtin_amdgcn_s_barrier();
        asm volatile("s_waitcnt lgkmcnt(0)" ::: "memory");
        __builtin_amdgcn_sched_barrier(0);
        __builtin_amdgcn_s_setprio(1);
#pragma unroll
        for (int mi = 0; mi < 2; mi++)
#pragma unroll
            for (int nt = 0; nt < 4; nt++)
#pragma unroll
                for (int kh = 0; kh < 2; kh++)
                    acc[2 + mi][nt] = __builtin_amdgcn_mfma_f32_16x16x32_bf16(
                        af[mi][kh], bfr[nt][kh], acc[2 + mi][nt], 0, 0, 0);
        __builtin_amdgcn_s_setprio(0);
        __builtin_amdgcn_s_barrier();
    }

    // ---- epilogue ----
    if (!TRANS_OUT) {
        // Y bf16 [16384][1536]: stage through swizzled LDS, 16B coalesced stores.
        unsigned short* eb = lds; // 128*256 shorts = 64 KB
#pragma unroll
        for (int mt = 0; mt < 4; mt++)
#pragma unroll
            for (int nt = 0; nt < 4; nt++) {
                int col = wn + nt * 16 + l16;
                float bv = bias[n0 + col];
                int cc = col >> 3, cw = col & 7;
#pragma unroll
                for (int r = 0; r < 4; r++) {
                    int row = wm + mt * 16 + quad * 4 + r;
                    eb[row * 256 + (((cc ^ (row & 7)) << 3) + cw)] = f2b(acc[mt][nt][r] + bv);
                }
            }
        __syncthreads();
        unsigned short* Y = (unsigned short*)Cout;
#pragma unroll
        for (int it = 0; it < 8; it++) {
            int cid = it * 512 + tid;        // 4096 16B-chunks
            int row = cid >> 5, j = cid & 31;
            bf16x8 v = *(const bf16x8*)&eb[row * 256 + ((j ^ (row & 7)) << 3)];
            *(bf16x8*)&Y[(size_t)(m0 + row) * N1 + n0 + j * 8] = v;
        }
    } else {
        // out f32 [16][512][1024]: transpose (n,s) via LDS, 2 passes of 128 n-rows.
        float* ef = (float*)lds; // 128*128 f32 = 64 KB
        int b = m0 >> 10, s0r = m0 & 1023;
        float* O = (float*)Cout;
#pragma unroll
        for (int p = 0; p < 2; p++) {
            if (((wid & 3) >> 1) == p) {
#pragma unroll
                for (int mt = 0; mt < 4; mt++)
#pragma unroll
                    for (int nt = 0; nt < 4; nt++) {
                        int nl = wn - p * 128 + nt * 16 + l16; // 0..127
                        float bv = bias[n0 + p * 128 + nl];
                        int c = (wm >> 2) + mt * 4 + quad;     // 0..31 (4-float chunks)
                        f32x4 v;
#pragma unroll
                        for (int r = 0; r < 4; r++) v[r] = acc[mt][nt][r] + bv;
                        *(f32x4*)&ef[nl * 128 + ((c ^ (nl & 7)) << 2)] = v;
                    }
            }
            __syncthreads();
#pragma unroll
            for (int it = 0; it < 8; it++) {
                int cid = it * 512 + tid;    // 4096 16B-chunks
                int nl = cid >> 5, j = cid & 31;
                f32x4 v = *(const f32x4*)&ef[nl * 128 + ((j ^ (nl & 7)) << 2)];
                *(f32x4*)&O[((size_t)(b * 512 + n0 + p * 128 + nl)) * 1024 + s0r + j * 4] = v;
            }
            if (p == 0) __syncthreads(); // before pass-1 overwrites
        }
    }

    // ---- fused a-sum accumulators (proven mapping: per-wave 64 m-rows, wm in {0,64}) ----
    if (DO_SUMS) {
        int b = m0 >> 10;
        int wlo = (m0 & 1023) >> 5; // first of 4 w-rows in this block
#pragma unroll
        for (int nt = 0; nt < 4; nt++) {
            int n = n0 + wn + nt * 16 + l16;
            float bv = bias[n];
            float tT = 0.f;
#pragma unroll
            for (int mt = 0; mt < 4; mt++)
#pragma unroll
                for (int r = 0; r < 4; r++) tT += acc[mt][nt][r] + bv;
            tT += __shfl_xor(tT, 16);
            tT += __shfl_xor(tT, 32);
            if (quad == 0) {
                atomicAdd(&Tsum[b * 1536 + n], tT);
                // h==0 rows: m_local = wm+{0,32} -> (mt 0,2, quad0, r0)
                float th0 = acc[0][nt][0] + acc[2][nt][0] + 2.f * bv;
                atomicAdd(&H0[b * 1536 + n], th0);
            }
            if (quad == 3) {
                // h==31 rows: m_local = wm+{31,63} -> (mt 1,3, quad3, r3)
                float th31 = acc[1][nt][3] + acc[3][nt][3] + 2.f * bv;
                atomicAdd(&H31[b * 1536 + n], th31);
            }
            if (wlo == 0 && wm == 0) { // w==0 slice: m_local < 32 -> mt 0,1
                float tc = 0.f;
#pragma unroll
                for (int mt = 0; mt < 2; mt++)
#pragma unroll
                    for (int r = 0; r < 4; r++) tc += acc[mt][nt][r] + bv;
                tc += __shfl_xor(tc, 16);
                tc += __shfl_xor(tc, 32);
                if (quad == 0) atomicAdd(&C0[b * 1536 + n], tc);
            }
            if (wlo == 28 && wm == 64) { // w==31 slice: m_local >= 96 -> mt 2,3
                float tc = 0.f;
#pragma unroll
                for (int mt = 2; mt < 4; mt++)
#pragma unroll
                    for (int r = 0; r < 4; r++) tc += acc[mt][nt][r] + bv;
                tc += __shfl_xor(tc, 16);
                tc += __shfl_xor(tc, 32);
                if (quad == 0) atomicAdd(&C31[b * 1536 + n], tc);
            }
        }
    }
}

// ---------- layer1 ----------
__global__ __launch_bounds__(256) void mlp_layer1(
    const float* __restrict__ sums, const float* __restrict__ wa,
    const float* __restrict__ ba, float* __restrict__ h)
{
    __shared__ float sa[512];
    int b = blockIdx.x >> 7;
    int t = threadIdx.x;
    const float* Tp   = sums;
    const float* H0p  = sums + 24576;
    const float* H31p = sums + 49152;
    const float* C0p  = sums + 73728;
    const float* C31p = sums + 98304;
#pragma unroll
    for (int j = 0; j < 2; j++) {
        int c = t + j * 256;
        int q = c >> 7;
        int n1 = b * 1536 + c;
        float t123 = Tp[n1] + Tp[n1 + 512] + Tp[n1 + 1024];
        float sC1 = C0p[n1] - C31p[n1];
        float sH1 = H0p[n1] - H31p[n1];
        float sC2 = C0p[n1 + 512] - C31p[n1 + 512];
        float sH2 = H0p[n1 + 512] - H31p[n1 + 512];
        float e = (q < 2) ? (sC1 + sH2) : (sH1 + sC2);
        sa[c] = t123 + ((q & 1) ? -e : e);
    }
    __syncthreads();
    int lane = t & 63, wid = t >> 6;
    int o = (blockIdx.x & 127) * 4 + wid;
    const float4* wr = (const float4*)(wa + (size_t)o * 512);
    float4 w0 = wr[lane * 2], w1v = wr[lane * 2 + 1];
    float4 a0 = ((const float4*)sa)[lane * 2], a1 = ((const float4*)sa)[lane * 2 + 1];
    float dot = w0.x * a0.x + w0.y * a0.y + w0.z * a0.z + w0.w * a0.w
              + w1v.x * a1.x + w1v.y * a1.y + w1v.z * a1.z + w1v.w * a1.w;
#pragma unroll
    for (int off = 32; off; off >>= 1) dot += __shfl_down(dot, off);
    if (lane == 0) {
        float v = dot + ba[o];
        h[b * 512 + o] = 0.5f * v * (1.0f + erff(v * 0.7071067811865475f));
    }
}

// ---------- layer2 ----------
__global__ __launch_bounds__(256) void mlp_layer2(
    const float* __restrict__ h, const float* __restrict__ wb,
    const float* __restrict__ bb, float* __restrict__ hat)
{
    int gw = (blockIdx.x * 256 + threadIdx.x) >> 6;
    int lane = threadIdx.x & 63;
    int b = gw / 1536;
    int o = gw - b * 1536;
    const float4* wr = (const float4*)(wb + (size_t)o * 512);
    const float4* hr = (const float4*)(h + (size_t)b * 512);
    float4 w0 = wr[lane * 2], w1 = wr[lane * 2 + 1];
    float4 h0 = hr[lane * 2], h1 = hr[lane * 2 + 1];
    float dot = w0.x * h0.x + w0.y * h0.y + w0.z * h0.z + w0.w * h0.w
              + w1.x * h1.x + w1.y * h1.y + w1.z * h1.z + w1.w * h1.w;
#pragma unroll
    for (int off = 32; off; off >>= 1) dot += __shfl_down(dot, off);
    if (lane == 0)
        hat[(size_t)b * 1536 + o] = dot + bb[o];
}

// ---------- combine (softmax inline) ----------
__global__ __launch_bounds__(256) void combine_softmax(
    const unsigned short* __restrict__ y, const float* __restrict__ hat,
    unsigned short* __restrict__ outT)
{
    int b = blockIdx.y;
    int w = blockIdx.x;          // 0..31
    int t = threadIdx.x;
    int h0 = (t >> 6) * 8;
    int c8 = (t & 63) * 8;
    int q = c8 >> 7;
    int dw1 = (q == 0) ? -1 : (q == 1) ? 1 : 0;
    int dh1 = (q == 2) ? -1 : (q == 3) ? 1 : 0;
    int dh2 = (q == 0) ? -1 : (q == 1) ? 1 : 0;
    int dw2 = (q == 2) ? -1 : (q == 3) ? 1 : 0;
    float g0[8], g1[8], g2[8];
#pragma unroll
    for (int j = 0; j < 8; j++) {
        int c = c8 + j;
        float h0v = hat[b * 1536 + c];
        float h1v = hat[b * 1536 + 512 + c];
        float h2v = hat[b * 1536 + 1024 + c];
        float mx = fmaxf(h0v, fmaxf(h1v, h2v));
        float e0 = __expf(h0v - mx), e1 = __expf(h1v - mx), e2 = __expf(h2v - mx);
        float inv = 1.0f / (e0 + e1 + e2);
        g0[j] = e0 * inv; g1[j] = e1 * inv; g2[j] = e2 * inv;
    }
    int w1i = min(max(w + dw1, 0), 31);
    int w2i = min(max(w + dw2, 0), 31);
    size_t base = (size_t)b * S_;
#pragma unroll
    for (int hh = 0; hh < 8; hh++) {
        int h = h0 + hh;
        int h1i = min(max(h + dh1, 0), 31);
        int h2i = min(max(h + dh2, 0), 31);
        uint4 u1 = *(const uint4*)&y[(base + w1i * 32 + h1i) * N1 + c8];
        uint4 u2 = *(const uint4*)&y[(base + w2i * 32 + h2i) * N1 + 512 + c8];
        uint4 u3 = *(const uint4*)&y[(base + w * 32 + h) * N1 + 1024 + c8];
        unsigned int p[4];
        const unsigned int* a1 = &u1.x;
        const unsigned int* a2 = &u2.x;
        const unsigned int* a3 = &u3.x;
#pragma unroll
        for (int k = 0; k < 4; k++) {
            int j = k * 2;
            float lo = g0[j] * b2f(a1[k]) + g1[j] * b2f(a2[k]) + g2[j] * b2f(a3[k]);
            float hi = g0[j + 1] * b2f(a1[k] >> 16) + g1[j + 1] * b2f(a2[k] >> 16) + g2[j + 1] * b2f(a3[k] >> 16);
            p[k] = (unsigned int)f2b(lo) | ((unsigned int)f2b(hi) << 16);
        }
        *(uint4*)&outT[(base + w * 32 + h) * 512 + c8] = make_uint4(p[0], p[1], p[2], p[3]);
    }
}

extern "C" void kernel_launch(void* const* d_in, const int* in_sizes, int n_in,
                              void* d_out, int out_size, void* d_ws, size_t ws_size,
                              hipStream_t stream) {
    const float* x  = (const float*)d_in[0];
    const float* w1 = (const float*)d_in[1];
    const float* b1 = (const float*)d_in[2];
    const float* wa = (const float*)d_in[3];
    const float* ba = (const float*)d_in[4];
    const float* wb = (const float*)d_in[5];
    const float* bb = (const float*)d_in[6];
    const float* w2 = (const float*)d_in[7];
    const float* b2 = (const float*)d_in[8];
    float* out = (float*)d_out;

    char* ws = (char*)d_ws;
    unsigned short* xT   = (unsigned short*)(ws);              // 16 MB (dead after gemm1)
    unsigned short* outT = (unsigned short*)(ws);              // aliases xT
    unsigned short* w1b  = (unsigned short*)(ws + 16777216);   // 1.5 MB
    unsigned short* w2b  = (unsigned short*)(ws + 18350080);   // 0.5 MB
    unsigned short* y    = (unsigned short*)(ws + 18874368);   // 48 MB: (B,S,3C) bf16
    float* sums          = (float*)(ws + 69206016);            // 5 x 96 KB
    float* h_buf         = (float*)(ws + 69697536);            // 32 KB
    float* hat_buf       = (float*)(ws + 69730304);            // 96 KB

    float* Tsum = sums;
    float* H0   = sums + 24576;
    float* H31  = sums + 49152;
    float* C0   = sums + 73728;
    float* C31  = sums + 98304;

    transpose_convert_x<<<dim3(32, 16, 17), dim3(32, 8), 0, stream>>>(
        x, xT, w1, w2, w1b, w2b, sums);
    gemm_2ph<false, true><<<dim3(128, 6), dim3(512), 0, stream>>>(
        xT, w1b, b1, (void*)y, Tsum, H0, H31, C0, C31);
    mlp_layer1<<<dim3(2048), dim3(256), 0, stream>>>(sums, wa, ba, h_buf);
    mlp_layer2<<<dim3(6144), dim3(256), 0, stream>>>(h_buf, wb, bb, hat_buf);
    combine_softmax<<<dim3(32, 16), dim3(256), 0, stream>>>(y, hat_buf, outT);
    gemm_2ph<true, false><<<dim3(128, 2), dim3(512), 0, stream>>>(
        outT, w2b, b2, (void*)out, nullptr, nullptr, nullptr, nullptr, nullptr);
}

// Round 4
// 175.312 us; speedup vs baseline: 1.1093x; 1.0114x over previous
//
#include <hip/hip_runtime.h>
#include <stdint.h>

typedef __bf16 bf16x8 __attribute__((ext_vector_type(8)));
typedef float f32x4 __attribute__((ext_vector_type(4)));

#define B_ 16
#define C_ 512
#define S_ 1024   // W*H = 32*32
#define N1 1536   // 3C

// ---------- bf16 helpers (manual RNE) ----------
__device__ inline unsigned short f2b(float f) {
    unsigned int u = __builtin_bit_cast(unsigned int, f);
    unsigned int lsb = (u >> 16) & 1u;
    u += 0x7fffu + lsb;
    return (unsigned short)(u >> 16);
}
__device__ inline float b2f(unsigned int s) {
    unsigned int u = (s & 0xffffu) << 16;
    return __builtin_bit_cast(float, u);
}

// async global->LDS, 16B per lane. LDS dest must be wave-uniform base + lane*16.
__device__ inline void gl_lds16(const unsigned short* g, unsigned short* l) {
    __builtin_amdgcn_global_load_lds(
        (const __attribute__((address_space(1))) void*)(g),
        (__attribute__((address_space(3))) void*)(l),
        16, 0, 0);
}

// ---------- prep: x (B,C,S) f32 -> xT (B,S,C) bf16 (vectorized), + fused misc ----------
// grid (16, 8, 17), block 256. z<16: transpose 64s x 64c tile. z==16: misc (grid-stride).
__global__ __launch_bounds__(256) void transpose_convert_x(
    const float* __restrict__ x, unsigned short* __restrict__ xT,
    const float* __restrict__ w1, const float* __restrict__ w2,
    unsigned short* __restrict__ w1b, unsigned short* __restrict__ w2b,
    float* __restrict__ sums)
{
    int t = threadIdx.x;
    if (blockIdx.z == 16) {
        int base = (blockIdx.y * 16 + blockIdx.x) * 256 + t; // 32768 threads
        for (int i = base; i < 292864; i += 32768) {
            if (i < 196608) {
                float4 v = ((const float4*)w1)[i];
                ((ushort4*)w1b)[i] = make_ushort4(f2b(v.x), f2b(v.y), f2b(v.z), f2b(v.w));
            } else if (i < 262144) {
                int j = i - 196608;
                float4 v = ((const float4*)w2)[j];
                ((ushort4*)w2b)[j] = make_ushort4(f2b(v.x), f2b(v.y), f2b(v.z), f2b(v.w));
            } else {
                int j = i - 262144;
                ((float4*)sums)[j] = make_float4(0.f, 0.f, 0.f, 0.f);
            }
        }
        return;
    }
    __shared__ float tile[64][68];
    int b = blockIdx.z;
    int c0 = blockIdx.y * 64;
    int s0 = blockIdx.x * 64;
    int r = t >> 2, q4 = t & 3;
    const float* xp = x + ((size_t)(b * C_ + c0 + r)) * S_ + s0;
#pragma unroll
    for (int k = 0; k < 4; k++) {
        float4 v = ((const float4*)xp)[q4 + 4 * k];
        *(float4*)&tile[r][(q4 + 4 * k) * 4] = v;
    }
    __syncthreads();
    int sr = t >> 2; // output s-row
    unsigned short* op = xT + ((size_t)(b * S_ + s0 + sr)) * C_ + c0;
#pragma unroll
    for (int kk = 0; kk < 2; kk++) {
        int chunk = q4 + 4 * kk;
        unsigned int pz[4];
#pragma unroll
        for (int i2 = 0; i2 < 4; i2++) {
            int c = chunk * 8 + i2 * 2;
            pz[i2] = (unsigned int)f2b(tile[c][sr]) | ((unsigned int)f2b(tile[c + 1][sr]) << 16);
        }
        *(uint4*)&op[chunk * 8] = make_uint4(pz[0], pz[1], pz[2], pz[3]);
    }
}

// ---------- gemm1: 128x256 tile, BK=64, 8 waves, 2-phase counted-vmcnt (R3, proven) ----------
template <bool TRANS_OUT, bool DO_SUMS>
__global__ __launch_bounds__(512, 2) void gemm_2ph(
    const unsigned short* __restrict__ A,
    const unsigned short* __restrict__ Wt,
    const float* __restrict__ bias,
    void* __restrict__ Cout,
    float* __restrict__ Tsum, float* __restrict__ H0, float* __restrict__ H31,
    float* __restrict__ C0, float* __restrict__ C31)
{
    __shared__ __align__(16) unsigned short lds[49152]; // 96 KB
    const int tid = threadIdx.x;
    const int lane = tid & 63, wid = tid >> 6;
    const int wm = (wid >> 2) * 64;   // 0 / 64
    const int wn = (wid & 3) * 64;    // 0,64,128,192
    const int quad = lane >> 4, l16 = lane & 15;
    const int m0 = blockIdx.x * 128;
    const int n0 = blockIdx.y * 256;
    const unsigned short* Ab = A + (size_t)m0 * 512;
    const unsigned short* Bb = Wt + (size_t)n0 * 512;

    f32x4 acc[4][4] = {};

    auto stageA = [&](int T) {
        unsigned short* dst = &lds[(T & 1) * 8192];
#pragma unroll
        for (int i = 0; i < 2; i++) {
            int ch = i * 512 + tid;
            int r = ch >> 3, kc = ch & 7;
            gl_lds16(Ab + (size_t)r * 512 + T * 64 + ((kc ^ (r & 7)) * 8), dst + ch * 8);
        }
    };
    auto stageB = [&](int T) {
        unsigned short* dst = &lds[16384 + (T & 1) * 16384];
#pragma unroll
        for (int i = 0; i < 4; i++) {
            int ch = i * 512 + tid;
            int r = ch >> 3, kc = ch & 7;
            gl_lds16(Bb + (size_t)r * 512 + T * 64 + ((kc ^ (r & 7)) * 8), dst + ch * 8);
        }
    };

    stageB(0); stageA(0); stageB(1);
    asm volatile("s_waitcnt vmcnt(4)" ::: "memory");
    __builtin_amdgcn_s_barrier();

    for (int T = 0; T < 8; T++) {
        const unsigned short* Asl = &lds[(T & 1) * 8192];
        const unsigned short* Bsl = &lds[16384 + (T & 1) * 16384];
        bf16x8 bfr[4][2], af[2][2];
        // ---- phase 0 ----
#pragma unroll
        for (int nt = 0; nt < 4; nt++)
#pragma unroll
            for (int kh = 0; kh < 2; kh++) {
                int rb = wn + nt * 16 + l16;
                bfr[nt][kh] = *(const bf16x8*)&Bsl[rb * 64 + (((kh * 4 + quad) ^ (rb & 7)) * 8)];
            }
#pragma unroll
        for (int mi = 0; mi < 2; mi++)
#pragma unroll
            for (int kh = 0; kh < 2; kh++) {
                int ra = wm + mi * 16 + l16;
                af[mi][kh] = *(const bf16x8*)&Asl[ra * 64 + (((kh * 4 + quad) ^ (ra & 7)) * 8)];
            }
        if (T < 7) stageA(T + 1);
        __builtin_amdgcn_s_barrier();
        asm volatile("s_waitcnt lgkmcnt(0)" ::: "memory");
        __builtin_amdgcn_sched_barrier(0);
        __builtin_amdgcn_s_setprio(1);
#pragma unroll
        for (int mi = 0; mi < 2; mi++)
#pragma unroll
            for (int nt = 0; nt < 4; nt++)
#pragma unroll
                for (int kh = 0; kh < 2; kh++)
                    acc[mi][nt] = __builtin_amdgcn_mfma_f32_16x16x32_bf16(
                        af[mi][kh], bfr[nt][kh], acc[mi][nt], 0, 0, 0);
        __builtin_amdgcn_s_setprio(0);
        __builtin_amdgcn_s_barrier();
        // ---- phase 1 ----
#pragma unroll
        for (int mi = 0; mi < 2; mi++)
#pragma unroll
            for (int kh = 0; kh < 2; kh++) {
                int ra = wm + (2 + mi) * 16 + l16;
                af[mi][kh] = *(const bf16x8*)&Asl[ra * 64 + (((kh * 4 + quad) ^ (ra & 7)) * 8)];
            }
        if (T < 6) {
            stageB(T + 2);
            asm volatile("s_waitcnt vmcnt(4)" ::: "memory");
        } else if (T == 6) {
            asm volatile("s_waitcnt vmcnt(0)" ::: "memory");
        }
        __builtin_amdgcn_s_barrier();
        asm volatile("s_waitcnt lgkmcnt(0)" ::: "memory");
        __builtin_amdgcn_sched_barrier(0);
        __builtin_amdgcn_s_setprio(1);
#pragma unroll
        for (int mi = 0; mi < 2; mi++)
#pragma unroll
            for (int nt = 0; nt < 4; nt++)
#pragma unroll
                for (int kh = 0; kh < 2; kh++)
                    acc[2 + mi][nt] = __builtin_amdgcn_mfma_f32_16x16x32_bf16(
                        af[mi][kh], bfr[nt][kh], acc[2 + mi][nt], 0, 0, 0);
        __builtin_amdgcn_s_setprio(0);
        __builtin_amdgcn_s_barrier();
    }

    // ---- epilogue ----
    if (!TRANS_OUT) {
        unsigned short* eb = lds;
#pragma unroll
        for (int mt = 0; mt < 4; mt++)
#pragma unroll
            for (int nt = 0; nt < 4; nt++) {
                int col = wn + nt * 16 + l16;
                float bv = bias[n0 + col];
                int cc = col >> 3, cw = col & 7;
#pragma unroll
                for (int r = 0; r < 4; r++) {
                    int row = wm + mt * 16 + quad * 4 + r;
                    eb[row * 256 + (((cc ^ (row & 7)) << 3) + cw)] = f2b(acc[mt][nt][r] + bv);
                }
            }
        __syncthreads();
        unsigned short* Y = (unsigned short*)Cout;
#pragma unroll
        for (int it = 0; it < 8; it++) {
            int cid = it * 512 + tid;
            int row = cid >> 5, j = cid & 31;
            bf16x8 v = *(const bf16x8*)&eb[row * 256 + ((j ^ (row & 7)) << 3)];
            *(bf16x8*)&Y[(size_t)(m0 + row) * N1 + n0 + j * 8] = v;
        }
    } else {
        float* ef = (float*)lds;
        int b = m0 >> 10, s0r = m0 & 1023;
        float* O = (float*)Cout;
#pragma unroll
        for (int p = 0; p < 2; p++) {
            if (((wid & 3) >> 1) == p) {
#pragma unroll
                for (int mt = 0; mt < 4; mt++)
#pragma unroll
                    for (int nt = 0; nt < 4; nt++) {
                        int nl = wn - p * 128 + nt * 16 + l16;
                        float bv = bias[n0 + p * 128 + nl];
                        int c = (wm >> 2) + mt * 4 + quad;
                        f32x4 v;
#pragma unroll
                        for (int r = 0; r < 4; r++) v[r] = acc[mt][nt][r] + bv;
                        *(f32x4*)&ef[nl * 128 + ((c ^ (nl & 7)) << 2)] = v;
                    }
            }
            __syncthreads();
#pragma unroll
            for (int it = 0; it < 8; it++) {
                int cid = it * 512 + tid;
                int nl = cid >> 5, j = cid & 31;
                f32x4 v = *(const f32x4*)&ef[nl * 128 + ((j ^ (nl & 7)) << 2)];
                *(f32x4*)&O[((size_t)(b * 512 + n0 + p * 128 + nl)) * 1024 + s0r + j * 4] = v;
            }
            if (p == 0) __syncthreads();
        }
    }

    if (DO_SUMS) {
        int b = m0 >> 10;
        int wlo = (m0 & 1023) >> 5;
#pragma unroll
        for (int nt = 0; nt < 4; nt++) {
            int n = n0 + wn + nt * 16 + l16;
            float bv = bias[n];
            float tT = 0.f;
#pragma unroll
            for (int mt = 0; mt < 4; mt++)
#pragma unroll
                for (int r = 0; r < 4; r++) tT += acc[mt][nt][r] + bv;
            tT += __shfl_xor(tT, 16);
            tT += __shfl_xor(tT, 32);
            if (quad == 0) {
                atomicAdd(&Tsum[b * 1536 + n], tT);
                float th0 = acc[0][nt][0] + acc[2][nt][0] + 2.f * bv;
                atomicAdd(&H0[b * 1536 + n], th0);
            }
            if (quad == 3) {
                float th31 = acc[1][nt][3] + acc[3][nt][3] + 2.f * bv;
                atomicAdd(&H31[b * 1536 + n], th31);
            }
            if (wlo == 0 && wm == 0) {
                float tc = 0.f;
#pragma unroll
                for (int mt = 0; mt < 2; mt++)
#pragma unroll
                    for (int r = 0; r < 4; r++) tc += acc[mt][nt][r] + bv;
                tc += __shfl_xor(tc, 16);
                tc += __shfl_xor(tc, 32);
                if (quad == 0) atomicAdd(&C0[b * 1536 + n], tc);
            }
            if (wlo == 28 && wm == 64) {
                float tc = 0.f;
#pragma unroll
                for (int mt = 2; mt < 4; mt++)
#pragma unroll
                    for (int r = 0; r < 4; r++) tc += acc[mt][nt][r] + bv;
                tc += __shfl_xor(tc, 16);
                tc += __shfl_xor(tc, 32);
                if (quad == 0) atomicAdd(&C31[b * 1536 + n], tc);
            }
        }
    }
}

// ---------- gemm2 with FUSED combine+softmax in A-staging ----------
// A[m][c] = g0[b,c]*y[shift1(s),c] + g1[b,c]*y[shift2(s),512+c] + g2[b,c]*y[s,1024+c]
// staged reg->LDS (T14): issue 6 y-loads in ph0, combine + 2 ds_write_b128 in ph1.
// B = w2b via gl_lds16 (as gemm1). Output: TRANS f32 via LDS.
__global__ __launch_bounds__(512, 2) void gemm2_fused(
    const unsigned short* __restrict__ Yg,
    const float* __restrict__ hat,
    const unsigned short* __restrict__ Wt,
    const float* __restrict__ bias,
    float* __restrict__ O)
{
    __shared__ __align__(16) unsigned short As[2 * 8192];   // 2 x 16 KB
    __shared__ __align__(16) unsigned short Bs[2 * 16384];  // 2 x 32 KB
    __shared__ float gs[3][512];                            // 6 KB
    const int tid = threadIdx.x;
    const int lane = tid & 63, wid = tid >> 6;
    const int wm = (wid >> 2) * 64;
    const int wn = (wid & 3) * 64;
    const int quad = lane >> 4, l16 = lane & 15;
    const int m0 = blockIdx.x * 128;
    const int n0 = blockIdx.y * 256;
    const int b = m0 >> 10, s0 = m0 & 1023, w0 = s0 >> 5;
    const int bq = b * 1024;
    const unsigned short* Bb = Wt + (size_t)n0 * 512;
    const int chunk = tid & 7, mpair = tid >> 3; // A-staging ownership: 2 m-rows x 8 c
    const int wA = w0 + ((mpair * 2) >> 5);      // both j share w,h base rows derived below

    f32x4 acc[4][4] = {};

    // gate precompute: one c per thread
    {
        int c = tid;
        float h0v = hat[b * 1536 + c];
        float h1v = hat[b * 1536 + 512 + c];
        float h2v = hat[b * 1536 + 1024 + c];
        float mx = fmaxf(h0v, fmaxf(h1v, h2v));
        float e0 = __expf(h0v - mx), e1 = __expf(h1v - mx), e2 = __expf(h2v - mx);
        float inv = 1.0f / (e0 + e1 + e2);
        gs[0][c] = e0 * inv; gs[1][c] = e1 * inv; gs[2][c] = e2 * inv;
    }
    __syncthreads();

    auto stageB = [&](int T) {
        unsigned short* dst = &Bs[(T & 1) * 16384];
#pragma unroll
        for (int i = 0; i < 4; i++) {
            int ch = i * 512 + tid;
            int r = ch >> 3, kc = ch & 7;
            gl_lds16(Bb + (size_t)r * 512 + T * 64 + ((kc ^ (r & 7)) * 8), dst + ch * 8);
        }
    };

    uint4 u1[2], u2[2], u3[2];
    auto issueA = [&](int Tn) {
        int q = Tn >> 1;
        int dw1 = (q == 0) ? -1 : (q == 1) ? 1 : 0;
        int dh1 = (q == 2) ? -1 : (q == 3) ? 1 : 0;
        int dh2 = (q == 0) ? -1 : (q == 1) ? 1 : 0;
        int dw2 = (q == 2) ? -1 : (q == 3) ? 1 : 0;
        int cg = Tn * 64 + chunk * 8;
#pragma unroll
        for (int j = 0; j < 2; j++) {
            int ml = mpair * 2 + j;
            int w = w0 + (ml >> 5), h = ml & 31;
            int r1 = bq + min(max(w + dw1, 0), 31) * 32 + min(max(h + dh1, 0), 31);
            int r2 = bq + min(max(w + dw2, 0), 31) * 32 + min(max(h + dh2, 0), 31);
            int r3 = bq + w * 32 + h;
            u1[j] = *(const uint4*)&Yg[(size_t)r1 * 1536 + cg];
            u2[j] = *(const uint4*)&Yg[(size_t)r2 * 1536 + 512 + cg];
            u3[j] = *(const uint4*)&Yg[(size_t)r3 * 1536 + 1024 + cg];
        }
    };
    auto writeA = [&](int Tn) {
        int cg = Tn * 64 + chunk * 8;
        float g0v[8], g1v[8], g2v[8];
        *(float4*)&g0v[0] = *(const float4*)&gs[0][cg];
        *(float4*)&g0v[4] = *(const float4*)&gs[0][cg + 4];
        *(float4*)&g1v[0] = *(const float4*)&gs[1][cg];
        *(float4*)&g1v[4] = *(const float4*)&gs[1][cg + 4];
        *(float4*)&g2v[0] = *(const float4*)&gs[2][cg];
        *(float4*)&g2v[4] = *(const float4*)&gs[2][cg + 4];
#pragma unroll
        for (int j = 0; j < 2; j++) {
            const unsigned int* a1 = (const unsigned int*)&u1[j];
            const unsigned int* a2 = (const unsigned int*)&u2[j];
            const unsigned int* a3 = (const unsigned int*)&u3[j];
            unsigned int p[4];
#pragma unroll
            for (int k = 0; k < 4; k++) {
                float lo = g0v[2 * k] * b2f(a1[k]) + g1v[2 * k] * b2f(a2[k]) + g2v[2 * k] * b2f(a3[k]);
                float hi = g0v[2 * k + 1] * b2f(a1[k] >> 16) + g1v[2 * k + 1] * b2f(a2[k] >> 16) + g2v[2 * k + 1] * b2f(a3[k] >> 16);
                p[k] = (unsigned int)f2b(lo) | ((unsigned int)f2b(hi) << 16);
            }
            int ml = mpair * 2 + j;
            *(uint4*)&As[(Tn & 1) * 8192 + ml * 64 + ((chunk ^ (ml & 7)) * 8)] = *(const uint4*)p;
        }
    };

    // prologue: B0, y0-loads, B1; wait B0+y0 (keep B1 in flight); build As[0]
    stageB(0);
    issueA(0);
    stageB(1);
    asm volatile("s_waitcnt vmcnt(4)" ::: "memory");
    writeA(0);
    asm volatile("s_waitcnt lgkmcnt(0)" ::: "memory");
    __builtin_amdgcn_s_barrier();

    for (int T = 0; T < 8; T++) {
        const unsigned short* Asl = &As[(T & 1) * 8192];
        const unsigned short* Bsl = &Bs[(T & 1) * 16384];
        bf16x8 bfr[4][2], af[2][2];
        // ---- phase 0 ----
#pragma unroll
        for (int nt = 0; nt < 4; nt++)
#pragma unroll
            for (int kh = 0; kh < 2; kh++) {
                int rb = wn + nt * 16 + l16;
                bfr[nt][kh] = *(const bf16x8*)&Bsl[rb * 64 + (((kh * 4 + quad) ^ (rb & 7)) * 8)];
            }
#pragma unroll
        for (int mi = 0; mi < 2; mi++)
#pragma unroll
            for (int kh = 0; kh < 2; kh++) {
                int ra = wm + mi * 16 + l16;
                af[mi][kh] = *(const bf16x8*)&Asl[ra * 64 + (((kh * 4 + quad) ^ (ra & 7)) * 8)];
            }
        if (T < 7) issueA(T + 1);
        __builtin_amdgcn_s_barrier();
        asm volatile("s_waitcnt lgkmcnt(0)" ::: "memory");
        __builtin_amdgcn_sched_barrier(0);
        __builtin_amdgcn_s_setprio(1);
#pragma unroll
        for (int mi = 0; mi < 2; mi++)
#pragma unroll
            for (int nt = 0; nt < 4; nt++)
#pragma unroll
                for (int kh = 0; kh < 2; kh++)
                    acc[mi][nt] = __builtin_amdgcn_mfma_f32_16x16x32_bf16(
                        af[mi][kh], bfr[nt][kh], acc[mi][nt], 0, 0, 0);
        __builtin_amdgcn_s_setprio(0);
        __builtin_amdgcn_s_barrier();
        // ---- phase 1 ----
#pragma unroll
        for (int mi = 0; mi < 2; mi++)
#pragma unroll
            for (int kh = 0; kh < 2; kh++) {
                int ra = wm + (2 + mi) * 16 + l16;
                af[mi][kh] = *(const bf16x8*)&Asl[ra * 64 + (((kh * 4 + quad) ^ (ra & 7)) * 8)];
            }
        if (T < 6) stageB(T + 2);
        if (T < 7) {
            if (T < 6) asm volatile("s_waitcnt vmcnt(4)" ::: "memory");
            else       asm volatile("s_waitcnt vmcnt(0)" ::: "memory");
            writeA(T + 1);
        }
        __builtin_amdgcn_s_barrier();
        asm volatile("s_waitcnt lgkmcnt(0)" ::: "memory");
        __builtin_amdgcn_sched_barrier(0);
        __builtin_amdgcn_s_setprio(1);
#pragma unroll
        for (int mi = 0; mi < 2; mi++)
#pragma unroll
            for (int nt = 0; nt < 4; nt++)
#pragma unroll
                for (int kh = 0; kh < 2; kh++)
                    acc[2 + mi][nt] = __builtin_amdgcn_mfma_f32_16x16x32_bf16(
                        af[mi][kh], bfr[nt][kh], acc[2 + mi][nt], 0, 0, 0);
        __builtin_amdgcn_s_setprio(0);
        __builtin_amdgcn_s_barrier();
    }

    // ---- epilogue: transpose (n,s) via LDS, 2 passes of 128 n-rows ----
    float* ef = (float*)Bs; // 64 KB
#pragma unroll
    for (int p = 0; p < 2; p++) {
        if (((wid & 3) >> 1) == p) {
#pragma unroll
            for (int mt = 0; mt < 4; mt++)
#pragma unroll
                for (int nt = 0; nt < 4; nt++) {
                    int nl = wn - p * 128 + nt * 16 + l16;
                    float bv = bias[n0 + p * 128 + nl];
                    int c = (wm >> 2) + mt * 4 + quad;
                    f32x4 v;
#pragma unroll
                    for (int r = 0; r < 4; r++) v[r] = acc[mt][nt][r] + bv;
                    *(f32x4*)&ef[nl * 128 + ((c ^ (nl & 7)) << 2)] = v;
                }
        }
        __syncthreads();
#pragma unroll
        for (int it = 0; it < 8; it++) {
            int cid = it * 512 + tid;
            int nl = cid >> 5, j = cid & 31;
            f32x4 v = *(const f32x4*)&ef[nl * 128 + ((j ^ (nl & 7)) << 2)];
            *(f32x4*)&O[((size_t)(b * 512 + n0 + p * 128 + nl)) * 1024 + s0 + j * 4] = v;
        }
        if (p == 0) __syncthreads();
    }
}

// ---------- layer1 ----------
__global__ __launch_bounds__(256) void mlp_layer1(
    const float* __restrict__ sums, const float* __restrict__ wa,
    const float* __restrict__ ba, float* __restrict__ h)
{
    __shared__ float sa[512];
    int b = blockIdx.x >> 7;
    int t = threadIdx.x;
    const float* Tp   = sums;
    const float* H0p  = sums + 24576;
    const float* H31p = sums + 49152;
    const float* C0p  = sums + 73728;
    const float* C31p = sums + 98304;
#pragma unroll
    for (int j = 0; j < 2; j++) {
        int c = t + j * 256;
        int q = c >> 7;
        int n1 = b * 1536 + c;
        float t123 = Tp[n1] + Tp[n1 + 512] + Tp[n1 + 1024];
        float sC1 = C0p[n1] - C31p[n1];
        float sH1 = H0p[n1] - H31p[n1];
        float sC2 = C0p[n1 + 512] - C31p[n1 + 512];
        float sH2 = H0p[n1 + 512] - H31p[n1 + 512];
        float e = (q < 2) ? (sC1 + sH2) : (sH1 + sC2);
        sa[c] = t123 + ((q & 1) ? -e : e);
    }
    __syncthreads();
    int lane = t & 63, wid = t >> 6;
    int o = (blockIdx.x & 127) * 4 + wid;
    const float4* wr = (const float4*)(wa + (size_t)o * 512);
    float4 w0 = wr[lane * 2], w1v = wr[lane * 2 + 1];
    float4 a0 = ((const float4*)sa)[lane * 2], a1 = ((const float4*)sa)[lane * 2 + 1];
    float dot = w0.x * a0.x + w0.y * a0.y + w0.z * a0.z + w0.w * a0.w
              + w1v.x * a1.x + w1v.y * a1.y + w1v.z * a1.z + w1v.w * a1.w;
#pragma unroll
    for (int off = 32; off; off >>= 1) dot += __shfl_down(dot, off);
    if (lane == 0) {
        float v = dot + ba[o];
        h[b * 512 + o] = 0.5f * v * (1.0f + erff(v * 0.7071067811865475f));
    }
}

// ---------- layer2: h staged in LDS; 16 o's per block (4 per wave) ----------
__global__ __launch_bounds__(256) void mlp_layer2(
    const float* __restrict__ h, const float* __restrict__ wb,
    const float* __restrict__ bb, float* __restrict__ hat)
{
    __shared__ float sh[512];
    int b = blockIdx.x / 96;
    int og = blockIdx.x - b * 96;
    int t = threadIdx.x;
    sh[t] = h[b * 512 + t];
    sh[t + 256] = h[b * 512 + 256 + t];
    __syncthreads();
    int lane = t & 63, wid = t >> 6;
    float4 a0 = ((const float4*)sh)[lane * 2], a1 = ((const float4*)sh)[lane * 2 + 1];
#pragma unroll
    for (int i = 0; i < 4; i++) {
        int o = og * 16 + wid * 4 + i;
        const float4* wr = (const float4*)(wb + (size_t)o * 512);
        float4 w0 = wr[lane * 2], w1 = wr[lane * 2 + 1];
        float dot = w0.x * a0.x + w0.y * a0.y + w0.z * a0.z + w0.w * a0.w
                  + w1.x * a1.x + w1.y * a1.y + w1.z * a1.z + w1.w * a1.w;
#pragma unroll
        for (int off = 32; off; off >>= 1) dot += __shfl_down(dot, off);
        if (lane == 0)
            hat[(size_t)b * 1536 + o] = dot + bb[o];
    }
}

extern "C" void kernel_launch(void* const* d_in, const int* in_sizes, int n_in,
                              void* d_out, int out_size, void* d_ws, size_t ws_size,
                              hipStream_t stream) {
    const float* x  = (const float*)d_in[0];
    const float* w1 = (const float*)d_in[1];
    const float* b1 = (const float*)d_in[2];
    const float* wa = (const float*)d_in[3];
    const float* ba = (const float*)d_in[4];
    const float* wb = (const float*)d_in[5];
    const float* bb = (const float*)d_in[6];
    const float* w2 = (const float*)d_in[7];
    const float* b2 = (const float*)d_in[8];
    float* out = (float*)d_out;

    char* ws = (char*)d_ws;
    unsigned short* xT   = (unsigned short*)(ws);              // 16 MB (dead after gemm1)
    unsigned short* w1b  = (unsigned short*)(ws + 16777216);   // 1.5 MB
    unsigned short* w2b  = (unsigned short*)(ws + 18350080);   // 0.5 MB
    unsigned short* y    = (unsigned short*)(ws + 18874368);   // 48 MB: (B,S,3C) bf16
    float* sums          = (float*)(ws + 69206016);            // 5 x 96 KB
    float* h_buf         = (float*)(ws + 69697536);            // 32 KB
    float* hat_buf       = (float*)(ws + 69730304);            // 96 KB

    float* Tsum = sums;
    float* H0   = sums + 24576;
    float* H31  = sums + 49152;
    float* C0   = sums + 73728;
    float* C31  = sums + 98304;

    transpose_convert_x<<<dim3(16, 8, 17), dim3(256), 0, stream>>>(
        x, xT, w1, w2, w1b, w2b, sums);
    gemm_2ph<false, true><<<dim3(128, 6), dim3(512), 0, stream>>>(
        xT, w1b, b1, (void*)y, Tsum, H0, H31, C0, C31);
    mlp_layer1<<<dim3(2048), dim3(256), 0, stream>>>(sums, wa, ba, h_buf);
    mlp_layer2<<<dim3(1536), dim3(256), 0, stream>>>(h_buf, wb, bb, hat_buf);
    gemm2_fused<<<dim3(128, 2), dim3(512), 0, stream>>>(
        y, hat_buf, w2b, b2, out);
}